// Round 11
// baseline (181.174 us; speedup 1.0000x reference)
//
#include <hip/hip_runtime.h>
#include <hip/hip_bf16.h>
#include <hip/hip_fp8.h>
#include <hip/hip_fp16.h>

#define N_NODESC 100000
#define N_EDGESC 1600000
#define FEATC 64
#define HEADSC 8
#define BATCHC 64
#define MAXLENC 2048
#define NBUCK 500          // 500 buckets x exactly 200 dst nodes
#define BSZ 200
#define HSZ 100            // dsts per k_aggf workgroup (half bucket)
#define CAPH 3072          // LDS edge capacity per half-bucket (mean 1600, sigma ~40)
#define K1B 1563           // k_pre transform blocks (64 nodes each)
#define HCHUNK 16          // int4-chunks of 256 per histogram block
#define K2B 98             // histogram blocks: 98*16*256 = 401408 >= 400000 int4s
#define CS_EPB 4096        // edges per k_csort block (512 thr x 8)
#define CSB 391            // ceil(1.6M / 4096)

typedef float f32x2 __attribute__((ext_vector_type(2)));

__device__ __forceinline__ float b2f(unsigned short u){
  union { unsigned u; float f; } c; c.u = ((unsigned)u) << 16; return c.f;
}
__device__ __forceinline__ unsigned short f2b(float f){
  union { float f; unsigned u; } c; c.f = f;
  unsigned r = c.u + 0x7fffu + ((c.u >> 16) & 1u);
  return (unsigned short)(r >> 16);
}
__device__ __forceinline__ int clampi(int v, int lo, int hi){
  return v < lo ? lo : (v > hi ? hi : v);
}
__device__ __forceinline__ void unpack8(uint4 v, float* o){
  o[0] = b2f((unsigned short)(v.x & 0xffff)); o[1] = b2f((unsigned short)(v.x >> 16));
  o[2] = b2f((unsigned short)(v.y & 0xffff)); o[3] = b2f((unsigned short)(v.y >> 16));
  o[4] = b2f((unsigned short)(v.z & 0xffff)); o[5] = b2f((unsigned short)(v.z >> 16));
  o[6] = b2f((unsigned short)(v.w & 0xffff)); o[7] = b2f((unsigned short)(v.w >> 16));
}
// 4 x fp8(e4m3, OCP on gfx950) packed in a dword -> 4 floats via v_cvt_pk_f32_fp8
__device__ __forceinline__ void cvt4(unsigned v, float* o){
  f32x2 lo = __builtin_amdgcn_cvt_pk_f32_fp8((int)v, false);
  f32x2 hi = __builtin_amdgcn_cvt_pk_f32_fp8((int)v, true);
  o[0] = lo.x; o[1] = lo.y; o[2] = hi.x; o[3] = hi.y;
}

// ---- K_pre v5: heterogeneous grid. Blocks [0,K1B): xw=x@W -> fp8 + a_src
// (fp16) + a_dst(fp32). v5: 64 nodes/block, 1 node/thread (R10 postmortem:
// LDS-staging didn't move it -> not load-latency-bound; 782 blocks = 12
// waves/CU was the cap. 1563 blocks = ~24 waves/CU). x-chunk in LDS (9-uint4
// row stride), W in LDS as raw bf16. Blocks [K1B,..): grid-persistent
// coarse histogram (98 blocks).
__global__ __launch_bounds__(256) void k_pre(
    const unsigned short* __restrict__ x, const unsigned short* __restrict__ W,
    const unsigned short* __restrict__ attS, const unsigned short* __restrict__ attD,
    const int* __restrict__ ei,
    unsigned char* __restrict__ xw8, __half* __restrict__ a_srch,
    float* __restrict__ a_dst, int* __restrict__ cc)
{
  __shared__ unsigned short Wh[64 * 64];      // W as raw bf16 (8 KB)
  __shared__ float as_s[64];
  __shared__ float ad_s[64];
  __shared__ uint4 xs_s[64 * 9];              // 64 node rows, 9-uint4 stride (9 KB)
  __shared__ int hh[NBUCK];
  int t = threadIdx.x;

  if (blockIdx.x >= K1B) {
    // ---- coarse histogram part (grid-persistent) ----
    for (int i = t; i < NBUCK; i += 256) hh[i] = 0;
    __syncthreads();
    int base4 = (blockIdx.x - K1B) * (HCHUNK * 256);
    #pragma unroll 4
    for (int it = 0; it < HCHUNK; it++) {
      int g = base4 + it * 256 + t;
      if (g < N_EDGESC / 4) {
        int4 d = ((const int4*)(ei + N_EDGESC))[g];
        atomicAdd(&hh[clampi(d.x, 0, N_NODESC - 1) / BSZ], 1);
        atomicAdd(&hh[clampi(d.y, 0, N_NODESC - 1) / BSZ], 1);
        atomicAdd(&hh[clampi(d.z, 0, N_NODESC - 1) / BSZ], 1);
        atomicAdd(&hh[clampi(d.w, 0, N_NODESC - 1) / BSZ], 1);
      }
    }
    __syncthreads();
    for (int i = t; i < NBUCK; i += 256) if (hh[i]) atomicAdd(&cc[i], hh[i]);
    return;
  }

  // ---- node transform part: 64 nodes/block, 1 node/thread ----
  {
    const uint4* W4 = (const uint4*)W;
    ((uint4*)Wh)[t]       = W4[t];
    ((uint4*)Wh)[t + 256] = W4[t + 256];      // 512 uint4 = 4096 ushort
  }
  if (t < 64) { as_s[t] = b2f(attS[t]); ad_s[t] = b2f(attD[t]); }
  {
    const uint4* x4 = (const uint4*)x;        // 8 uint4 per node row
    int gbase = blockIdx.x * 512;             // 64 nodes * 8
    #pragma unroll
    for (int r = 0; r < 2; r++) {
      int idx = t + r * 256;                  // 0..511
      int nl = idx >> 3, i = idx & 7;
      uint4 v = make_uint4(0u, 0u, 0u, 0u);
      int gi = gbase + idx;
      if (gi < N_NODESC * 8) v = x4[gi];
      xs_s[nl * 9 + i] = v;
    }
  }
  __syncthreads();

  int g    = t & 3;
  int slot = t >> 2;                          // local node (0..63)
  int n    = blockIdx.x * 64 + slot;

  float acc[16];
  #pragma unroll
  for (int c = 0; c < 16; c++) acc[c] = 0.f;

  const uint4* Wq = (const uint4*)Wh;         // 8 uint4 per W row
  for (int i = 0; i < 8; i++) {
    float xu[8];
    unpack8(xs_s[slot * 9 + i], xu);
    #pragma unroll
    for (int u = 0; u < 8; u++) {
      int k = i * 8 + u;
      float wf[16];
      unpack8(Wq[k * 8 + g * 2 + 0], wf);
      unpack8(Wq[k * 8 + g * 2 + 1], wf + 8);
      float xk = xu[u];
      #pragma unroll
      for (int c = 0; c < 16; c++) acc[c] += xk * wf[c];
    }
  }

  if (n < N_NODESC) {
    union { unsigned u[4]; unsigned char b[16]; } pk;
    #pragma unroll
    for (int c = 0; c < 16; c++)
      pk.b[c] = (unsigned char)__hip_fp8_e4m3(acc[c]).__x;
    uint4 o; o.x = pk.u[0]; o.y = pk.u[1]; o.z = pk.u[2]; o.w = pk.u[3];
    *((uint4*)(xw8 + (size_t)n * 64 + g * 16)) = o;

    #pragma unroll
    for (int hl = 0; hl < 2; hl++) {
      int h = g * 2 + hl;
      float sa = 0.f, sd = 0.f;
      #pragma unroll
      for (int c = 0; c < 8; c++) {
        sa += acc[hl * 8 + c] * as_s[h * 8 + c];
        sd += acc[hl * 8 + c] * ad_s[h * 8 + c];
      }
      a_srch[n * 8 + h] = __float2half(sa);
      a_dst[n * 8 + h] = sd;
    }
  }
}

// ---- K_csort v2 (lite): 391 blocks x 512 thr x 8 edges. R10 postmortem:
// k_aggf treats bucket segments as UNORDERED, so the old within-block
// counting sort (2nd scan + 48KB sorted/sbk staging + re-scatter pass)
// was pure waste. Keep cc-scan (for global base) + LDS histogram; reserve
// a run per bucket via one gcur atomic; write each edge DIRECTLY to its
// reserved slot via an LDS cursor. LDS 60KB -> 6KB, barriers ~40 -> ~22.
__global__ __launch_bounds__(512) void k_csort(const int* __restrict__ ei,
                                               const int* __restrict__ cc,
                                               int* __restrict__ gcur,
                                               unsigned* __restrict__ cs,
                                               int* __restrict__ boff) {
  __shared__ int bst[512];
  __shared__ int h[NBUCK];
  __shared__ int lcur[NBUCK];
  int t = threadIdx.x;
  int base = blockIdx.x * CS_EPB;
  for (int i = t; i < NBUCK; i += 512) h[i] = 0;
  int myc = (t < NBUCK) ? cc[t] : 0;
  bst[t] = myc;
  __syncthreads();
  for (int off = 1; off < 512; off <<= 1) {
    int v = bst[t];
    if (t >= off) v += bst[t - off];
    __syncthreads();
    bst[t] = v;
    __syncthreads();
  }
  if (blockIdx.x == 0 && t < NBUCK) boff[t] = bst[t] - myc;

  unsigned pk[8]; int bk[8];
  #pragma unroll
  for (int k = 0; k < 8; k++) {
    int idx = base + k * 512 + t;
    bk[k] = -1;
    if (idx < N_EDGESC) {
      int s = clampi(ei[idx], 0, N_NODESC - 1);
      int d = clampi(ei[N_EDGESC + idx], 0, N_NODESC - 1);
      int b = d / BSZ;
      pk[k] = (unsigned)s | ((unsigned)(d - b * BSZ) << 17);
      bk[k] = b;
      atomicAdd(&h[b], 1);
    }
  }
  __syncthreads();
  if (t < NBUCK && h[t])
    lcur[t] = (bst[t] - myc) + atomicAdd(&gcur[t], h[t]);
  __syncthreads();
  #pragma unroll
  for (int k = 0; k < 8; k++) if (bk[k] >= 0) {
    int p = atomicAdd(&lcur[bk[k]], 1);
    cs[p] = pk[k];
  }
}

// ---- K_aggf v6: TWO 512-thread WGs per bucket (100 dsts each), 1000 WGs.
// FOUR lanes own one dst: lane = (dst-slot s=l>>2, quad q=l&3). Quad q covers
// channels 16q..16q+15 = heads 2q,2q+1, so each lane computes its own two
// edge weights -> ZERO cross-lane ops anywhere. Per edge per lane: one uint4
// xw8 load (4 lanes = full 64B row) + one half2 a_src load; 2-deep rotation.
__global__ __launch_bounds__(512) void k_aggf(
    const __half* __restrict__ a_srch, const float* __restrict__ a_dst,
    const unsigned char* __restrict__ xw8, const unsigned* __restrict__ cs,
    const int* __restrict__ cc, const int* __restrict__ boff,
    const unsigned short* __restrict__ bias, unsigned short* __restrict__ nembh)
{
  __shared__ int lcnt[128], loff[128], lcur[128];
  __shared__ int ssrc[CAPH];
  int t = threadIdx.x;
  int b = blockIdx.x >> 1;
  int dlo = (blockIdx.x & 1) * HSZ;   // this WG's dst-range within the bucket
  int base = boff[b];
  int cnt  = cc[b];
  if (cnt > 12 * 512) cnt = 12 * 512;  // 6144 cap (astronomically safe)

  if (t < 128) lcnt[t] = 0;
  __syncthreads();

  // read the bucket's edges, keep those whose dl is in [dlo, dlo+HSZ)
  unsigned ce[12];
  #pragma unroll
  for (int j = 0; j < 12; j++) {
    int i = t + j * 512;
    ce[j] = 0xFFFFFFFFu;
    if (i < cnt) {
      unsigned e = cs[base + i];
      int dl = (int)(e >> 17);
      if (dl >= dlo && dl < dlo + HSZ) {
        ce[j] = e;
        atomicAdd(&lcnt[dl - dlo], 1);
      }
    }
  }
  __syncthreads();
  if (t < 128) loff[t] = lcnt[t];
  __syncthreads();
  for (int off = 1; off < 128; off <<= 1) {
    int v = 0;
    if (t < 128) { v = loff[t]; if (t >= off) v += loff[t - off]; }
    __syncthreads();
    if (t < 128) loff[t] = v;
    __syncthreads();
  }
  if (t < 128) { int ex = loff[t] - lcnt[t]; loff[t] = ex; lcur[t] = ex; }
  __syncthreads();
  #pragma unroll
  for (int j = 0; j < 12; j++) if (ce[j] != 0xFFFFFFFFu) {
    int p = atomicAdd(&lcur[(int)(ce[j] >> 17) - dlo], 1);
    if (p < CAPH) ssrc[p] = (int)(ce[j] & 0x1FFFFu);
  }
  __syncthreads();

  int wv = t >> 6;        // wave 0..7
  int l  = t & 63;
  int s  = l >> 2;        // dst slot within wave (0..15)
  int q  = l & 3;         // channel quad: channels 16q..16q+15, heads 2q,2q+1
  int d2 = s * 8 + wv;    // 0..127, balanced across waves

  if (d2 < HSZ) {
    int dst = b * BSZ + dlo + d2;

    // self weights for heads 2q, 2q+1
    float2 sa2 = __half22float2(*(const __half2*)(a_srch + dst * 8 + q * 2));
    float2 ad2 = *(const float2*)(a_dst + dst * 8 + q * 2);
    float z0 = sa2.x + ad2.x, z1 = sa2.y + ad2.y;
    float den0 = __expf(fmaxf(z0, 0.2f * z0));
    float den1 = __expf(fmaxf(z1, 0.2f * z1));

    // acc init = selfw * x_self (16 channels)
    uint4 xs = *(const uint4*)(xw8 + (size_t)dst * 64 + q * 16);
    float xv[16];
    cvt4(xs.x, xv); cvt4(xs.y, xv + 4); cvt4(xs.z, xv + 8); cvt4(xs.w, xv + 12);
    float acc[16];
    #pragma unroll
    for (int c = 0; c < 8; c++) { acc[c] = den0 * xv[c]; acc[8 + c] = den1 * xv[8 + c]; }

    int beg = loff[d2]; if (beg > CAPH) beg = CAPH;
    int end2 = beg + lcnt[d2]; if (end2 > CAPH) end2 = CAPH;

    // 2-deep rotation: indices from LDS, loads independent
    int nA = (beg < end2) ? ssrc[beg] : 0;
    int nB = (beg + 1 < end2) ? ssrc[beg + 1] : 0;
    __half2 aA = *(const __half2*)(a_srch + nA * 8 + q * 2);
    uint4   xA = *(const uint4*)(xw8 + (size_t)nA * 64 + q * 16);
    __half2 aB = *(const __half2*)(a_srch + nB * 8 + q * 2);
    uint4   xB = *(const uint4*)(xw8 + (size_t)nB * 64 + q * 16);

    for (int i = beg; i < end2; i++) {
      float2 af = __half22float2(aA);
      uint4  xc = xA;
      aA = aB; xA = xB;
      int nn = (i + 2 < end2) ? ssrc[i + 2] : 0;
      aB = *(const __half2*)(a_srch + nn * 8 + q * 2);
      xB = *(const uint4*)(xw8 + (size_t)nn * 64 + q * 16);

      float e0 = af.x + ad2.x, e1 = af.y + ad2.y;
      float w0 = __expf(fmaxf(e0, 0.2f * e0));
      float w1 = __expf(fmaxf(e1, 0.2f * e1));
      den0 += w0; den1 += w1;
      float yv[16];
      cvt4(xc.x, yv); cvt4(xc.y, yv + 4); cvt4(xc.z, yv + 8); cvt4(xc.w, yv + 12);
      #pragma unroll
      for (int c = 0; c < 8; c++) { acc[c] += w0 * yv[c]; acc[8 + c] += w1 * yv[8 + c]; }
    }

    // epilogue: divide, bias, relu, pack 16 bf16 = 32B
    float inv0 = __builtin_amdgcn_rcpf(den0);
    float inv1 = __builtin_amdgcn_rcpf(den1);
    uint4 bb0 = ((const uint4*)bias)[q * 2];
    uint4 bb1 = ((const uint4*)bias)[q * 2 + 1];
    unsigned bw[8] = {bb0.x, bb0.y, bb0.z, bb0.w, bb1.x, bb1.y, bb1.z, bb1.w};
    unsigned ow[8];
    #pragma unroll
    for (int p = 0; p < 8; p++) {
      float inv = (p < 4) ? inv0 : inv1;
      float v0 = acc[p * 2]     * inv + b2f((unsigned short)(bw[p] & 0xffff));
      float v1 = acc[p * 2 + 1] * inv + b2f((unsigned short)(bw[p] >> 16));
      v0 = fmaxf(v0, 0.f); v1 = fmaxf(v1, 0.f);
      ow[p] = (unsigned)f2b(v0) | ((unsigned)f2b(v1) << 16);
    }
    uint4 o0 = make_uint4(ow[0], ow[1], ow[2], ow[3]);
    uint4 o1 = make_uint4(ow[4], ow[5], ow[6], ow[7]);
    ((uint4*)nembh)[(size_t)dst * 8 + q * 2]     = o0;
    ((uint4*)nembh)[(size_t)dst * 8 + q * 2 + 1] = o1;
  }
}

// ---- K6: padded gather from bf16 nemb -> fp32 out + seq_lengths tail ----
__global__ __launch_bounds__(256) void k6_gather(
    const unsigned short* __restrict__ nembh, const int* __restrict__ traj,
    const int* __restrict__ lens, float* __restrict__ out)
{
  int gid = blockIdx.x * 256 + threadIdx.x;
  if (gid < BATCHC * MAXLENC * 16) {
    int b = gid >> 15;
    int rem = gid & 32767;
    int l = rem >> 4;
    int ch = rem & 15;
    int len = clampi(lens[b], 0, MAXLENC);
    float4 val = make_float4(0.f, 0.f, 0.f, 0.f);
    if (l < len) {
      int node = clampi(traj[b * MAXLENC + l], 0, N_NODESC - 1);
      uint2 q = ((const uint2*)nembh)[(size_t)node * 16 + ch];
      val = make_float4(b2f((unsigned short)(q.x & 0xffff)),
                        b2f((unsigned short)(q.x >> 16)),
                        b2f((unsigned short)(q.y & 0xffff)),
                        b2f((unsigned short)(q.y >> 16)));
    }
    ((float4*)out)[gid] = val;
  }
  if (gid < BATCHC) {
    out[(size_t)BATCHC * MAXLENC * FEATC + gid] = (float)lens[gid];
  }
}

extern "C" void kernel_launch(void* const* d_in, const int* in_sizes, int n_in,
                              void* d_out, int out_size, void* d_ws, size_t ws_size,
                              hipStream_t stream) {
  const unsigned short* x    = (const unsigned short*)d_in[0];
  const unsigned short* W    = (const unsigned short*)d_in[1];
  const unsigned short* attS = (const unsigned short*)d_in[2];
  const unsigned short* attD = (const unsigned short*)d_in[3];
  const unsigned short* bias = (const unsigned short*)d_in[4];
  const int* ei   = (const int*)d_in[5];
  const int* traj = (const int*)d_in[6];
  const int* lens = (const int*)d_in[7];
  float* out = (float*)d_out;

  // workspace (float units, max 9.9M floats = 39.6 MB; under proven size):
  //  [0, 1.6M)        xw fp8 (6.4M bytes)
  //  [3.2M, 3.6M)     a_src fp16 (800k half)
  //  [4.0M, 4.8M)     a_dst fp32
  //  [4.9M, +512)     ccounts (500)
  //  [+512, +1024)    gcur (500, zero-based)   -- one memset covers both
  //  [+1024, +1536)   boff (500, written by k_csort block 0)
  //  [5.0M, 6.6M)     cs (packed uint, 1.6M)
  //  [6.7M, 9.9M)     nemb bf16 (6.4M ushort)
  float* F = (float*)d_ws;
  unsigned char* xw8 = (unsigned char*)d_ws;
  __half* a_srch = (__half*)(F + 3200000);
  float* a_dst   = F + 4000000;
  int* ccounts   = (int*)(F + 4900000);
  int* gcur      = (int*)(F + 4900000) + 512;
  int* boff      = (int*)(F + 4900000) + 1024;
  unsigned* cs   = (unsigned*)(F + 5000000);
  unsigned short* nembh = (unsigned short*)(F + 6700000);

  hipMemsetAsync(ccounts, 0, 1024 * sizeof(int), stream);
  k_pre<<<K1B + K2B, 256, 0, stream>>>(
      x, W, attS, attD, ei, xw8, a_srch, a_dst, ccounts);
  k_csort<<<CSB, 512, 0, stream>>>(ei, ccounts, gcur, cs, boff);
  k_aggf<<<NBUCK * 2, 512, 0, stream>>>(a_srch, a_dst, xw8, cs, ccounts, boff, bias, nembh);
  k6_gather<<<(BATCHC * MAXLENC * 16 + 255) / 256, 256, 0, stream>>>(nembh, traj, lens, out);
}

// Round 12
// 172.367 us; speedup vs baseline: 1.0511x; 1.0511x over previous
//
#include <hip/hip_runtime.h>
#include <hip/hip_bf16.h>
#include <hip/hip_fp8.h>
#include <hip/hip_fp16.h>

#define N_NODESC 100000
#define N_EDGESC 1600000
#define FEATC 64
#define HEADSC 8
#define BATCHC 64
#define MAXLENC 2048
#define NBUCK 500          // 500 buckets x exactly 200 dst nodes
#define BSZ 200
#define HSZ 100            // dsts per k_aggf workgroup (half bucket)
#define CAPH 3072          // LDS edge capacity per half-bucket (mean 1600, sigma ~40)
#define P3_EDGES 8192      // edges per k_csort workgroup (1024 thr x 8)
#define K1B 1563           // k_pre transform blocks (64 nodes each)
#define HCHUNK 16          // int4-chunks of 256 per histogram block
#define K2B 98             // histogram blocks: 98*16*256 = 401408 >= 400000 int4s

typedef float f32x2 __attribute__((ext_vector_type(2)));

__device__ __forceinline__ float b2f(unsigned short u){
  union { unsigned u; float f; } c; c.u = ((unsigned)u) << 16; return c.f;
}
__device__ __forceinline__ unsigned short f2b(float f){
  union { float f; unsigned u; } c; c.f = f;
  unsigned r = c.u + 0x7fffu + ((c.u >> 16) & 1u);
  return (unsigned short)(r >> 16);
}
__device__ __forceinline__ int clampi(int v, int lo, int hi){
  return v < lo ? lo : (v > hi ? hi : v);
}
__device__ __forceinline__ void unpack8(uint4 v, float* o){
  o[0] = b2f((unsigned short)(v.x & 0xffff)); o[1] = b2f((unsigned short)(v.x >> 16));
  o[2] = b2f((unsigned short)(v.y & 0xffff)); o[3] = b2f((unsigned short)(v.y >> 16));
  o[4] = b2f((unsigned short)(v.z & 0xffff)); o[5] = b2f((unsigned short)(v.z >> 16));
  o[6] = b2f((unsigned short)(v.w & 0xffff)); o[7] = b2f((unsigned short)(v.w >> 16));
}
// 4 x fp8(e4m3, OCP on gfx950) packed in a dword -> 4 floats via v_cvt_pk_f32_fp8
__device__ __forceinline__ void cvt4(unsigned v, float* o){
  f32x2 lo = __builtin_amdgcn_cvt_pk_f32_fp8((int)v, false);
  f32x2 hi = __builtin_amdgcn_cvt_pk_f32_fp8((int)v, true);
  o[0] = lo.x; o[1] = lo.y; o[2] = hi.x; o[3] = hi.y;
}

// ---- K_pre v5: heterogeneous grid. Blocks [0,K1B): xw=x@W -> fp8 + a_src
// (fp16) + a_dst(fp32). 64 nodes/block, 1 node/thread (A/B vs v4's 2/thread:
// 1563 blocks = ~6 blocks/CU removes the grid cap on occupancy). x-chunk in
// LDS (9-uint4 row stride), W in LDS as raw bf16. Blocks [K1B,..):
// grid-persistent coarse histogram (98 blocks).
__global__ __launch_bounds__(256) void k_pre(
    const unsigned short* __restrict__ x, const unsigned short* __restrict__ W,
    const unsigned short* __restrict__ attS, const unsigned short* __restrict__ attD,
    const int* __restrict__ ei,
    unsigned char* __restrict__ xw8, __half* __restrict__ a_srch,
    float* __restrict__ a_dst, int* __restrict__ cc)
{
  __shared__ unsigned short Wh[64 * 64];      // W as raw bf16 (8 KB)
  __shared__ float as_s[64];
  __shared__ float ad_s[64];
  __shared__ uint4 xs_s[64 * 9];              // 64 node rows, 9-uint4 stride (9 KB)
  __shared__ int hh[NBUCK];
  int t = threadIdx.x;

  if (blockIdx.x >= K1B) {
    // ---- coarse histogram part (grid-persistent) ----
    for (int i = t; i < NBUCK; i += 256) hh[i] = 0;
    __syncthreads();
    int base4 = (blockIdx.x - K1B) * (HCHUNK * 256);
    #pragma unroll 4
    for (int it = 0; it < HCHUNK; it++) {
      int g = base4 + it * 256 + t;
      if (g < N_EDGESC / 4) {
        int4 d = ((const int4*)(ei + N_EDGESC))[g];
        atomicAdd(&hh[clampi(d.x, 0, N_NODESC - 1) / BSZ], 1);
        atomicAdd(&hh[clampi(d.y, 0, N_NODESC - 1) / BSZ], 1);
        atomicAdd(&hh[clampi(d.z, 0, N_NODESC - 1) / BSZ], 1);
        atomicAdd(&hh[clampi(d.w, 0, N_NODESC - 1) / BSZ], 1);
      }
    }
    __syncthreads();
    for (int i = t; i < NBUCK; i += 256) if (hh[i]) atomicAdd(&cc[i], hh[i]);
    return;
  }

  // ---- node transform part: 64 nodes/block, 1 node/thread ----
  {
    const uint4* W4 = (const uint4*)W;
    ((uint4*)Wh)[t]       = W4[t];
    ((uint4*)Wh)[t + 256] = W4[t + 256];      // 512 uint4 = 4096 ushort
  }
  if (t < 64) { as_s[t] = b2f(attS[t]); ad_s[t] = b2f(attD[t]); }
  {
    const uint4* x4 = (const uint4*)x;        // 8 uint4 per node row
    int gbase = blockIdx.x * 512;             // 64 nodes * 8
    #pragma unroll
    for (int r = 0; r < 2; r++) {
      int idx = t + r * 256;                  // 0..511
      int nl = idx >> 3, i = idx & 7;
      uint4 v = make_uint4(0u, 0u, 0u, 0u);
      int gi = gbase + idx;
      if (gi < N_NODESC * 8) v = x4[gi];
      xs_s[nl * 9 + i] = v;
    }
  }
  __syncthreads();

  int g    = t & 3;
  int slot = t >> 2;                          // local node (0..63)
  int n    = blockIdx.x * 64 + slot;

  float acc[16];
  #pragma unroll
  for (int c = 0; c < 16; c++) acc[c] = 0.f;

  const uint4* Wq = (const uint4*)Wh;         // 8 uint4 per W row
  for (int i = 0; i < 8; i++) {
    float xu[8];
    unpack8(xs_s[slot * 9 + i], xu);
    #pragma unroll
    for (int u = 0; u < 8; u++) {
      int k = i * 8 + u;
      float wf[16];
      unpack8(Wq[k * 8 + g * 2 + 0], wf);
      unpack8(Wq[k * 8 + g * 2 + 1], wf + 8);
      float xk = xu[u];
      #pragma unroll
      for (int c = 0; c < 16; c++) acc[c] += xk * wf[c];
    }
  }

  if (n < N_NODESC) {
    union { unsigned u[4]; unsigned char b[16]; } pk;
    #pragma unroll
    for (int c = 0; c < 16; c++)
      pk.b[c] = (unsigned char)__hip_fp8_e4m3(acc[c]).__x;
    uint4 o; o.x = pk.u[0]; o.y = pk.u[1]; o.z = pk.u[2]; o.w = pk.u[3];
    *((uint4*)(xw8 + (size_t)n * 64 + g * 16)) = o;

    #pragma unroll
    for (int hl = 0; hl < 2; hl++) {
      int h = g * 2 + hl;
      float sa = 0.f, sd = 0.f;
      #pragma unroll
      for (int c = 0; c < 8; c++) {
        sa += acc[hl * 8 + c] * as_s[h * 8 + c];
        sd += acc[hl * 8 + c] * ad_s[h * 8 + c];
      }
      a_srch[n * 8 + h] = __float2half(sa);
      a_dst[n * 8 + h] = sd;
    }
  }
}

// ---- K_csort v1 (REVERTED from R11's "lite"): 1024 thr, 8192 edges/wg.
// R11 postmortem: the LDS staging sort is the WRITE-COALESCING mechanism —
// consecutive threads write consecutive cs addresses within each bucket run.
// Direct per-edge scatter (v2) decoalesced 1.6M writes and cost ~10us.
// Block 0 publishes the exclusive bucket-prefix to boff[]. ----
__global__ __launch_bounds__(1024) void k_csort(const int* __restrict__ ei,
                                                const int* __restrict__ cc,
                                                int* __restrict__ gcur,
                                                unsigned* __restrict__ cs,
                                                int* __restrict__ boff) {
  __shared__ int bst[512];
  __shared__ int h[NBUCK], lst[NBUCK], lcur[NBUCK], gb[NBUCK];
  __shared__ int sc[512];
  __shared__ unsigned sorted[P3_EDGES];
  __shared__ unsigned short sbk[P3_EDGES];
  int t = threadIdx.x;
  int base = blockIdx.x * P3_EDGES;
  for (int i = t; i < NBUCK; i += 1024) h[i] = 0;
  int myc = 0;
  if (t < 512) { myc = (t < NBUCK) ? cc[t] : 0; bst[t] = myc; }
  __syncthreads();
  for (int off = 1; off < 512; off <<= 1) {
    int v = 0;
    if (t < 512) { v = bst[t]; if (t >= off) v += bst[t - off]; }
    __syncthreads();
    if (t < 512) bst[t] = v;
    __syncthreads();
  }
  if (blockIdx.x == 0 && t < NBUCK) boff[t] = bst[t] - myc;
  unsigned pk[8]; int bk[8];
  #pragma unroll
  for (int k = 0; k < 8; k++) {
    int idx = base + k * 1024 + t;
    bk[k] = -1;
    if (idx < N_EDGESC) {
      int s = clampi(ei[idx], 0, N_NODESC - 1);
      int d = clampi(ei[N_EDGESC + idx], 0, N_NODESC - 1);
      int b = d / BSZ;
      pk[k] = (unsigned)s | ((unsigned)(d - b * BSZ) << 17);
      bk[k] = b;
      atomicAdd(&h[b], 1);
    }
  }
  __syncthreads();
  if (t < 512) sc[t] = (t < NBUCK) ? h[t] : 0;
  __syncthreads();
  for (int off = 1; off < 512; off <<= 1) {
    int v = 0;
    if (t < 512) { v = sc[t]; if (t >= off) v += sc[t - off]; }
    __syncthreads();
    if (t < 512) sc[t] = v;
    __syncthreads();
  }
  if (t < NBUCK) {
    int ex = sc[t] - h[t];
    lst[t] = ex; lcur[t] = ex;
    if (h[t]) gb[t] = (bst[t] - myc) + atomicAdd(&gcur[t], h[t]);
  }
  __syncthreads();
  #pragma unroll
  for (int k = 0; k < 8; k++) if (bk[k] >= 0) {
    int p = atomicAdd(&lcur[bk[k]], 1);
    sorted[p] = pk[k];
    sbk[p] = (unsigned short)bk[k];
  }
  __syncthreads();
  int cnt = N_EDGESC - base; if (cnt > P3_EDGES) cnt = P3_EDGES;
  #pragma unroll
  for (int k = 0; k < 8; k++) {
    int i = k * 1024 + t;
    if (i < cnt) {
      int b = sbk[i];
      cs[gb[b] + (i - lst[b])] = sorted[i];
    }
  }
}

// ---- K_aggf v6: TWO 512-thread WGs per bucket (100 dsts each), 1000 WGs.
// FOUR lanes own one dst: lane = (dst-slot s=l>>2, quad q=l&3). Quad q covers
// channels 16q..16q+15 = heads 2q,2q+1, so each lane computes its own two
// edge weights -> ZERO cross-lane ops anywhere. Per edge per lane: one uint4
// xw8 load (4 lanes = full 64B row) + one half2 a_src load; 2-deep rotation.
__global__ __launch_bounds__(512) void k_aggf(
    const __half* __restrict__ a_srch, const float* __restrict__ a_dst,
    const unsigned char* __restrict__ xw8, const unsigned* __restrict__ cs,
    const int* __restrict__ cc, const int* __restrict__ boff,
    const unsigned short* __restrict__ bias, unsigned short* __restrict__ nembh)
{
  __shared__ int lcnt[128], loff[128], lcur[128];
  __shared__ int ssrc[CAPH];
  int t = threadIdx.x;
  int b = blockIdx.x >> 1;
  int dlo = (blockIdx.x & 1) * HSZ;   // this WG's dst-range within the bucket
  int base = boff[b];
  int cnt  = cc[b];
  if (cnt > 12 * 512) cnt = 12 * 512;  // 6144 cap (astronomically safe)

  if (t < 128) lcnt[t] = 0;
  __syncthreads();

  // read the bucket's edges, keep those whose dl is in [dlo, dlo+HSZ)
  unsigned ce[12];
  #pragma unroll
  for (int j = 0; j < 12; j++) {
    int i = t + j * 512;
    ce[j] = 0xFFFFFFFFu;
    if (i < cnt) {
      unsigned e = cs[base + i];
      int dl = (int)(e >> 17);
      if (dl >= dlo && dl < dlo + HSZ) {
        ce[j] = e;
        atomicAdd(&lcnt[dl - dlo], 1);
      }
    }
  }
  __syncthreads();
  if (t < 128) loff[t] = lcnt[t];
  __syncthreads();
  for (int off = 1; off < 128; off <<= 1) {
    int v = 0;
    if (t < 128) { v = loff[t]; if (t >= off) v += loff[t - off]; }
    __syncthreads();
    if (t < 128) loff[t] = v;
    __syncthreads();
  }
  if (t < 128) { int ex = loff[t] - lcnt[t]; loff[t] = ex; lcur[t] = ex; }
  __syncthreads();
  #pragma unroll
  for (int j = 0; j < 12; j++) if (ce[j] != 0xFFFFFFFFu) {
    int p = atomicAdd(&lcur[(int)(ce[j] >> 17) - dlo], 1);
    if (p < CAPH) ssrc[p] = (int)(ce[j] & 0x1FFFFu);
  }
  __syncthreads();

  int wv = t >> 6;        // wave 0..7
  int l  = t & 63;
  int s  = l >> 2;        // dst slot within wave (0..15)
  int q  = l & 3;         // channel quad: channels 16q..16q+15, heads 2q,2q+1
  int d2 = s * 8 + wv;    // 0..127, balanced across waves

  if (d2 < HSZ) {
    int dst = b * BSZ + dlo + d2;

    // self weights for heads 2q, 2q+1
    float2 sa2 = __half22float2(*(const __half2*)(a_srch + dst * 8 + q * 2));
    float2 ad2 = *(const float2*)(a_dst + dst * 8 + q * 2);
    float z0 = sa2.x + ad2.x, z1 = sa2.y + ad2.y;
    float den0 = __expf(fmaxf(z0, 0.2f * z0));
    float den1 = __expf(fmaxf(z1, 0.2f * z1));

    // acc init = selfw * x_self (16 channels)
    uint4 xs = *(const uint4*)(xw8 + (size_t)dst * 64 + q * 16);
    float xv[16];
    cvt4(xs.x, xv); cvt4(xs.y, xv + 4); cvt4(xs.z, xv + 8); cvt4(xs.w, xv + 12);
    float acc[16];
    #pragma unroll
    for (int c = 0; c < 8; c++) { acc[c] = den0 * xv[c]; acc[8 + c] = den1 * xv[8 + c]; }

    int beg = loff[d2]; if (beg > CAPH) beg = CAPH;
    int end2 = beg + lcnt[d2]; if (end2 > CAPH) end2 = CAPH;

    // 2-deep rotation: indices from LDS, loads independent
    int nA = (beg < end2) ? ssrc[beg] : 0;
    int nB = (beg + 1 < end2) ? ssrc[beg + 1] : 0;
    __half2 aA = *(const __half2*)(a_srch + nA * 8 + q * 2);
    uint4   xA = *(const uint4*)(xw8 + (size_t)nA * 64 + q * 16);
    __half2 aB = *(const __half2*)(a_srch + nB * 8 + q * 2);
    uint4   xB = *(const uint4*)(xw8 + (size_t)nB * 64 + q * 16);

    for (int i = beg; i < end2; i++) {
      float2 af = __half22float2(aA);
      uint4  xc = xA;
      aA = aB; xA = xB;
      int nn = (i + 2 < end2) ? ssrc[i + 2] : 0;
      aB = *(const __half2*)(a_srch + nn * 8 + q * 2);
      xB = *(const uint4*)(xw8 + (size_t)nn * 64 + q * 16);

      float e0 = af.x + ad2.x, e1 = af.y + ad2.y;
      float w0 = __expf(fmaxf(e0, 0.2f * e0));
      float w1 = __expf(fmaxf(e1, 0.2f * e1));
      den0 += w0; den1 += w1;
      float yv[16];
      cvt4(xc.x, yv); cvt4(xc.y, yv + 4); cvt4(xc.z, yv + 8); cvt4(xc.w, yv + 12);
      #pragma unroll
      for (int c = 0; c < 8; c++) { acc[c] += w0 * yv[c]; acc[8 + c] += w1 * yv[8 + c]; }
    }

    // epilogue: divide, bias, relu, pack 16 bf16 = 32B
    float inv0 = __builtin_amdgcn_rcpf(den0);
    float inv1 = __builtin_amdgcn_rcpf(den1);
    uint4 bb0 = ((const uint4*)bias)[q * 2];
    uint4 bb1 = ((const uint4*)bias)[q * 2 + 1];
    unsigned bw[8] = {bb0.x, bb0.y, bb0.z, bb0.w, bb1.x, bb1.y, bb1.z, bb1.w};
    unsigned ow[8];
    #pragma unroll
    for (int p = 0; p < 8; p++) {
      float inv = (p < 4) ? inv0 : inv1;
      float v0 = acc[p * 2]     * inv + b2f((unsigned short)(bw[p] & 0xffff));
      float v1 = acc[p * 2 + 1] * inv + b2f((unsigned short)(bw[p] >> 16));
      v0 = fmaxf(v0, 0.f); v1 = fmaxf(v1, 0.f);
      ow[p] = (unsigned)f2b(v0) | ((unsigned)f2b(v1) << 16);
    }
    uint4 o0 = make_uint4(ow[0], ow[1], ow[2], ow[3]);
    uint4 o1 = make_uint4(ow[4], ow[5], ow[6], ow[7]);
    ((uint4*)nembh)[(size_t)dst * 8 + q * 2]     = o0;
    ((uint4*)nembh)[(size_t)dst * 8 + q * 2 + 1] = o1;
  }
}

// ---- K6: padded gather from bf16 nemb -> fp32 out + seq_lengths tail ----
__global__ __launch_bounds__(256) void k6_gather(
    const unsigned short* __restrict__ nembh, const int* __restrict__ traj,
    const int* __restrict__ lens, float* __restrict__ out)
{
  int gid = blockIdx.x * 256 + threadIdx.x;
  if (gid < BATCHC * MAXLENC * 16) {
    int b = gid >> 15;
    int rem = gid & 32767;
    int l = rem >> 4;
    int ch = rem & 15;
    int len = clampi(lens[b], 0, MAXLENC);
    float4 val = make_float4(0.f, 0.f, 0.f, 0.f);
    if (l < len) {
      int node = clampi(traj[b * MAXLENC + l], 0, N_NODESC - 1);
      uint2 q = ((const uint2*)nembh)[(size_t)node * 16 + ch];
      val = make_float4(b2f((unsigned short)(q.x & 0xffff)),
                        b2f((unsigned short)(q.x >> 16)),
                        b2f((unsigned short)(q.y & 0xffff)),
                        b2f((unsigned short)(q.y >> 16)));
    }
    ((float4*)out)[gid] = val;
  }
  if (gid < BATCHC) {
    out[(size_t)BATCHC * MAXLENC * FEATC + gid] = (float)lens[gid];
  }
}

extern "C" void kernel_launch(void* const* d_in, const int* in_sizes, int n_in,
                              void* d_out, int out_size, void* d_ws, size_t ws_size,
                              hipStream_t stream) {
  const unsigned short* x    = (const unsigned short*)d_in[0];
  const unsigned short* W    = (const unsigned short*)d_in[1];
  const unsigned short* attS = (const unsigned short*)d_in[2];
  const unsigned short* attD = (const unsigned short*)d_in[3];
  const unsigned short* bias = (const unsigned short*)d_in[4];
  const int* ei   = (const int*)d_in[5];
  const int* traj = (const int*)d_in[6];
  const int* lens = (const int*)d_in[7];
  float* out = (float*)d_out;

  // workspace (float units, max 9.9M floats = 39.6 MB; under proven size):
  //  [0, 1.6M)        xw fp8 (6.4M bytes)
  //  [3.2M, 3.6M)     a_src fp16 (800k half)
  //  [4.0M, 4.8M)     a_dst fp32
  //  [4.9M, +512)     ccounts (500)
  //  [+512, +1024)    gcur (500, zero-based)   -- one memset covers both
  //  [+1024, +1536)   boff (500, written by k_csort block 0)
  //  [5.0M, 6.6M)     cs (packed uint, 1.6M)
  //  [6.7M, 9.9M)     nemb bf16 (6.4M ushort)
  float* F = (float*)d_ws;
  unsigned char* xw8 = (unsigned char*)d_ws;
  __half* a_srch = (__half*)(F + 3200000);
  float* a_dst   = F + 4000000;
  int* ccounts   = (int*)(F + 4900000);
  int* gcur      = (int*)(F + 4900000) + 512;
  int* boff      = (int*)(F + 4900000) + 1024;
  unsigned* cs   = (unsigned*)(F + 5000000);
  unsigned short* nembh = (unsigned short*)(F + 6700000);

  hipMemsetAsync(ccounts, 0, 1024 * sizeof(int), stream);
  k_pre<<<K1B + K2B, 256, 0, stream>>>(
      x, W, attS, attD, ei, xw8, a_srch, a_dst, ccounts);
  k_csort<<<(N_EDGESC + P3_EDGES - 1) / P3_EDGES, 1024, 0, stream>>>(ei, ccounts, gcur, cs, boff);
  k_aggf<<<NBUCK * 2, 512, 0, stream>>>(a_srch, a_dst, xw8, cs, ccounts, boff, bias, nembh);
  k6_gather<<<(BATCHC * MAXLENC * 16 + 255) / 256, 256, 0, stream>>>(nembh, traj, lens, out);
}

// Round 13
// 160.388 us; speedup vs baseline: 1.1296x; 1.0747x over previous
//
#include <hip/hip_runtime.h>
#include <hip/hip_bf16.h>
#include <hip/hip_fp8.h>
#include <hip/hip_fp16.h>

#define N_NODESC 100000
#define N_EDGESC 1600000
#define FEATC 64
#define HEADSC 8
#define BATCHC 64
#define MAXLENC 2048
#define NBUCK 500          // 500 buckets x exactly 200 dst nodes
#define BSZ 200
#define HSZ 100            // dsts per k_aggf workgroup (half bucket)
#define CAPH 3072          // LDS edge capacity per half-bucket (mean 1600, sigma ~40)
#define P3_EDGES 8192      // edges per k_csort workgroup (1024 thr x 8)
#define K1B 1563           // k_pre transform blocks (64 nodes each)
#define HCHUNK 16          // int4-chunks of 256 per histogram block
#define K2B 98             // histogram blocks: 98*16*256 = 401408 >= 400000 int4s

typedef float f32x2 __attribute__((ext_vector_type(2)));
typedef float f32x4 __attribute__((ext_vector_type(4)));
typedef short bf16x8 __attribute__((ext_vector_type(8)));

__device__ __forceinline__ float b2f(unsigned short u){
  union { unsigned u; float f; } c; c.u = ((unsigned)u) << 16; return c.f;
}
__device__ __forceinline__ unsigned short f2b(float f){
  union { float f; unsigned u; } c; c.f = f;
  unsigned r = c.u + 0x7fffu + ((c.u >> 16) & 1u);
  return (unsigned short)(r >> 16);
}
__device__ __forceinline__ int clampi(int v, int lo, int hi){
  return v < lo ? lo : (v > hi ? hi : v);
}
__device__ __forceinline__ void unpack8(uint4 v, float* o){
  o[0] = b2f((unsigned short)(v.x & 0xffff)); o[1] = b2f((unsigned short)(v.x >> 16));
  o[2] = b2f((unsigned short)(v.y & 0xffff)); o[3] = b2f((unsigned short)(v.y >> 16));
  o[4] = b2f((unsigned short)(v.z & 0xffff)); o[5] = b2f((unsigned short)(v.z >> 16));
  o[6] = b2f((unsigned short)(v.w & 0xffff)); o[7] = b2f((unsigned short)(v.w >> 16));
}
// 4 x fp8(e4m3, OCP on gfx950) packed in a dword -> 4 floats via v_cvt_pk_f32_fp8
__device__ __forceinline__ void cvt4(unsigned v, float* o){
  f32x2 lo = __builtin_amdgcn_cvt_pk_f32_fp8((int)v, false);
  f32x2 hi = __builtin_amdgcn_cvt_pk_f32_fp8((int)v, true);
  o[0] = lo.x; o[1] = lo.y; o[2] = hi.x; o[3] = hi.y;
}

// ---- K_pre v6 (MFMA): heterogeneous grid. Blocks [0,K1B): xw=x@W via
// v_mfma_f32_16x16x32_bf16. 64 nodes/block, 4 waves; wave w owns nodes
// w*16..w*16+15 x all 64 out-ch (4 c-tiles x 2 k-blocks = 8 MFMA).
// A-frag: lane l reads x_s[node rlo][k=kb*32+khi*8..+7] (b128, 9-uint4 row
// pad -> conflict-free). B-frag from W^T staged in LDS (same padding).
// f32 tile parked in LDS (68-f32 row pad), then the proven fp8-pack +
// a_src/a_dst epilogue runs unchanged. Rationale (R12): scalar transform is
// VALU-bound at ~820M lane-ops (~10.4us floor, ~21 measured); MFMA moves
// the MACs to the matrix pipe -> memory/staging-bound (~22MB, ~5us floor).
// C/D layout (guide-verified): col=lane&15, row=(lane>>4)*4+reg.
// Blocks [K1B,..): grid-persistent coarse histogram (98 blocks).
__global__ __launch_bounds__(256) void k_pre(
    const unsigned short* __restrict__ x, const unsigned short* __restrict__ W,
    const unsigned short* __restrict__ attS, const unsigned short* __restrict__ attD,
    const int* __restrict__ ei,
    unsigned char* __restrict__ xw8, __half* __restrict__ a_srch,
    float* __restrict__ a_dst, int* __restrict__ cc)
{
  __shared__ uint4 wt_s[64 * 9];              // W^T bf16, 9-uint4 row stride (9.2 KB)
  __shared__ uint4 xs_s[64 * 9];              // x tile bf16, 9-uint4 row stride (9.2 KB)
  __shared__ float out_s[64 * 68];            // f32 result tile, padded (17.4 KB)
  __shared__ float as_s[64];
  __shared__ float ad_s[64];
  __shared__ int hh[NBUCK];
  int t = threadIdx.x;

  if (blockIdx.x >= K1B) {
    // ---- coarse histogram part (grid-persistent) ----
    for (int i = t; i < NBUCK; i += 256) hh[i] = 0;
    __syncthreads();
    int base4 = (blockIdx.x - K1B) * (HCHUNK * 256);
    #pragma unroll 4
    for (int it = 0; it < HCHUNK; it++) {
      int g = base4 + it * 256 + t;
      if (g < N_EDGESC / 4) {
        int4 d = ((const int4*)(ei + N_EDGESC))[g];
        atomicAdd(&hh[clampi(d.x, 0, N_NODESC - 1) / BSZ], 1);
        atomicAdd(&hh[clampi(d.y, 0, N_NODESC - 1) / BSZ], 1);
        atomicAdd(&hh[clampi(d.z, 0, N_NODESC - 1) / BSZ], 1);
        atomicAdd(&hh[clampi(d.w, 0, N_NODESC - 1) / BSZ], 1);
      }
    }
    __syncthreads();
    for (int i = t; i < NBUCK; i += 256) if (hh[i]) atomicAdd(&cc[i], hh[i]);
    return;
  }

  // ---- stage: W row-major (temp, aliases out_s), x tile, att vectors ----
  unsigned short* wrow = (unsigned short*)out_s;   // 8KB temp inside out_s
  {
    const uint4* W4 = (const uint4*)W;
    ((uint4*)wrow)[t]       = W4[t];
    ((uint4*)wrow)[t + 256] = W4[t + 256];    // 512 uint4 = 4096 bf16
  }
  if (t < 64) { as_s[t] = b2f(attS[t]); ad_s[t] = b2f(attD[t]); }
  {
    const uint4* x4 = (const uint4*)x;        // 8 uint4 per node row
    int gbase = blockIdx.x * 512;             // 64 nodes * 8
    #pragma unroll
    for (int r = 0; r < 2; r++) {
      int idx = t + r * 256;                  // 0..511
      int nl = idx >> 3, i = idx & 7;
      uint4 v = make_uint4(0u, 0u, 0u, 0u);
      int gi = gbase + idx;
      if (gi < N_NODESC * 8) v = x4[gi];
      xs_s[nl * 9 + i] = v;
    }
  }
  __syncthreads();

  // ---- transpose W -> wt_s[c][k] (bf16, padded rows) ----
  {
    int c = t >> 2, kq = t & 3;               // 16 k's per thread
    unsigned short tmp[16];
    #pragma unroll
    for (int e = 0; e < 16; e++) tmp[e] = wrow[(kq * 16 + e) * 64 + c];
    wt_s[c * 9 + kq * 2]     = *(uint4*)&tmp[0];
    wt_s[c * 9 + kq * 2 + 1] = *(uint4*)&tmp[8];
  }
  __syncthreads();

  // ---- MFMA: wave w -> nodes w*16..+15, all 64 out channels ----
  {
    int l   = t & 63;
    int w   = t >> 6;
    int rlo = l & 15;                         // node row within slab / B col
    int khi = l >> 4;                         // k-octet selector (0..3)

    union { uint4 u; bf16x8 h; } a0, a1, bb;
    a0.u = xs_s[(w * 16 + rlo) * 9 + 0 + khi];      // k = 0*32 + khi*8 ..+7
    a1.u = xs_s[(w * 16 + rlo) * 9 + 4 + khi];      // k = 32  + khi*8 ..+7

    f32x4 acc[4];
    #pragma unroll
    for (int ct = 0; ct < 4; ct++) acc[ct] = (f32x4){0.f, 0.f, 0.f, 0.f};

    #pragma unroll
    for (int ct = 0; ct < 4; ct++) {
      bb.u = wt_s[(ct * 16 + rlo) * 9 + 0 + khi];   // B: col=ct*16+rlo, kb=0
      acc[ct] = __builtin_amdgcn_mfma_f32_16x16x32_bf16(a0.h, bb.h, acc[ct], 0, 0, 0);
      bb.u = wt_s[(ct * 16 + rlo) * 9 + 4 + khi];   // kb=1
      acc[ct] = __builtin_amdgcn_mfma_f32_16x16x32_bf16(a1.h, bb.h, acc[ct], 0, 0, 0);
    }

    // D layout: col = lane&15 (within c-tile), row = (lane>>4)*4 + reg
    __syncthreads();   // wrow (aliased with out_s) fully consumed by all waves
    #pragma unroll
    for (int ct = 0; ct < 4; ct++)
      #pragma unroll
      for (int j = 0; j < 4; j++)
        out_s[(w * 16 + khi * 4 + j) * 68 + ct * 16 + rlo] = acc[ct][j];
  }
  __syncthreads();

  // ---- epilogue (unchanged structure): fp8 pack + a_src/a_dst dots ----
  {
    int g  = t & 3;
    int nl = t >> 2;
    int n  = blockIdx.x * 64 + nl;
    if (n < N_NODESC) {
      float vals[16];
      #pragma unroll
      for (int q = 0; q < 4; q++)
        *(float4*)&vals[q * 4] = *(float4*)&out_s[nl * 68 + g * 16 + q * 4];

      union { unsigned u[4]; unsigned char b[16]; } pk;
      #pragma unroll
      for (int c = 0; c < 16; c++)
        pk.b[c] = (unsigned char)__hip_fp8_e4m3(vals[c]).__x;
      uint4 o; o.x = pk.u[0]; o.y = pk.u[1]; o.z = pk.u[2]; o.w = pk.u[3];
      *((uint4*)(xw8 + (size_t)n * 64 + g * 16)) = o;

      #pragma unroll
      for (int hl = 0; hl < 2; hl++) {
        int h = g * 2 + hl;
        float sa = 0.f, sd = 0.f;
        #pragma unroll
        for (int c = 0; c < 8; c++) {
          sa += vals[hl * 8 + c] * as_s[h * 8 + c];
          sd += vals[hl * 8 + c] * ad_s[h * 8 + c];
        }
        a_srch[n * 8 + h] = __float2half(sa);
        a_dst[n * 8 + h] = sd;
      }
    }
  }
}

// ---- K_csort v1: 1024 thr, 8192 edges/wg. LDS staging sort = the
// write-coalescing mechanism (R11 lesson: direct scatter cost ~10us).
// Block 0 publishes the exclusive bucket-prefix to boff[]. ----
__global__ __launch_bounds__(1024) void k_csort(const int* __restrict__ ei,
                                                const int* __restrict__ cc,
                                                int* __restrict__ gcur,
                                                unsigned* __restrict__ cs,
                                                int* __restrict__ boff) {
  __shared__ int bst[512];
  __shared__ int h[NBUCK], lst[NBUCK], lcur[NBUCK], gb[NBUCK];
  __shared__ int sc[512];
  __shared__ unsigned sorted[P3_EDGES];
  __shared__ unsigned short sbk[P3_EDGES];
  int t = threadIdx.x;
  int base = blockIdx.x * P3_EDGES;
  for (int i = t; i < NBUCK; i += 1024) h[i] = 0;
  int myc = 0;
  if (t < 512) { myc = (t < NBUCK) ? cc[t] : 0; bst[t] = myc; }
  __syncthreads();
  for (int off = 1; off < 512; off <<= 1) {
    int v = 0;
    if (t < 512) { v = bst[t]; if (t >= off) v += bst[t - off]; }
    __syncthreads();
    if (t < 512) bst[t] = v;
    __syncthreads();
  }
  if (blockIdx.x == 0 && t < NBUCK) boff[t] = bst[t] - myc;
  unsigned pk[8]; int bk[8];
  #pragma unroll
  for (int k = 0; k < 8; k++) {
    int idx = base + k * 1024 + t;
    bk[k] = -1;
    if (idx < N_EDGESC) {
      int s = clampi(ei[idx], 0, N_NODESC - 1);
      int d = clampi(ei[N_EDGESC + idx], 0, N_NODESC - 1);
      int b = d / BSZ;
      pk[k] = (unsigned)s | ((unsigned)(d - b * BSZ) << 17);
      bk[k] = b;
      atomicAdd(&h[b], 1);
    }
  }
  __syncthreads();
  if (t < 512) sc[t] = (t < NBUCK) ? h[t] : 0;
  __syncthreads();
  for (int off = 1; off < 512; off <<= 1) {
    int v = 0;
    if (t < 512) { v = sc[t]; if (t >= off) v += sc[t - off]; }
    __syncthreads();
    if (t < 512) sc[t] = v;
    __syncthreads();
  }
  if (t < NBUCK) {
    int ex = sc[t] - h[t];
    lst[t] = ex; lcur[t] = ex;
    if (h[t]) gb[t] = (bst[t] - myc) + atomicAdd(&gcur[t], h[t]);
  }
  __syncthreads();
  #pragma unroll
  for (int k = 0; k < 8; k++) if (bk[k] >= 0) {
    int p = atomicAdd(&lcur[bk[k]], 1);
    sorted[p] = pk[k];
    sbk[p] = (unsigned short)bk[k];
  }
  __syncthreads();
  int cnt = N_EDGESC - base; if (cnt > P3_EDGES) cnt = P3_EDGES;
  #pragma unroll
  for (int k = 0; k < 8; k++) {
    int i = k * 1024 + t;
    if (i < cnt) {
      int b = sbk[i];
      cs[gb[b] + (i - lst[b])] = sorted[i];
    }
  }
}

// ---- K_aggf v6: TWO 512-thread WGs per bucket (100 dsts each), 1000 WGs.
// FOUR lanes own one dst: lane = (dst-slot s=l>>2, quad q=l&3). Quad q covers
// channels 16q..16q+15 = heads 2q,2q+1, so each lane computes its own two
// edge weights -> ZERO cross-lane ops anywhere. Per edge per lane: one uint4
// xw8 load (4 lanes = full 64B row) + one half2 a_src load; 2-deep rotation.
__global__ __launch_bounds__(512) void k_aggf(
    const __half* __restrict__ a_srch, const float* __restrict__ a_dst,
    const unsigned char* __restrict__ xw8, const unsigned* __restrict__ cs,
    const int* __restrict__ cc, const int* __restrict__ boff,
    const unsigned short* __restrict__ bias, unsigned short* __restrict__ nembh)
{
  __shared__ int lcnt[128], loff[128], lcur[128];
  __shared__ int ssrc[CAPH];
  int t = threadIdx.x;
  int b = blockIdx.x >> 1;
  int dlo = (blockIdx.x & 1) * HSZ;   // this WG's dst-range within the bucket
  int base = boff[b];
  int cnt  = cc[b];
  if (cnt > 12 * 512) cnt = 12 * 512;  // 6144 cap (astronomically safe)

  if (t < 128) lcnt[t] = 0;
  __syncthreads();

  // read the bucket's edges, keep those whose dl is in [dlo, dlo+HSZ)
  unsigned ce[12];
  #pragma unroll
  for (int j = 0; j < 12; j++) {
    int i = t + j * 512;
    ce[j] = 0xFFFFFFFFu;
    if (i < cnt) {
      unsigned e = cs[base + i];
      int dl = (int)(e >> 17);
      if (dl >= dlo && dl < dlo + HSZ) {
        ce[j] = e;
        atomicAdd(&lcnt[dl - dlo], 1);
      }
    }
  }
  __syncthreads();
  if (t < 128) loff[t] = lcnt[t];
  __syncthreads();
  for (int off = 1; off < 128; off <<= 1) {
    int v = 0;
    if (t < 128) { v = loff[t]; if (t >= off) v += loff[t - off]; }
    __syncthreads();
    if (t < 128) loff[t] = v;
    __syncthreads();
  }
  if (t < 128) { int ex = loff[t] - lcnt[t]; loff[t] = ex; lcur[t] = ex; }
  __syncthreads();
  #pragma unroll
  for (int j = 0; j < 12; j++) if (ce[j] != 0xFFFFFFFFu) {
    int p = atomicAdd(&lcur[(int)(ce[j] >> 17) - dlo], 1);
    if (p < CAPH) ssrc[p] = (int)(ce[j] & 0x1FFFFu);
  }
  __syncthreads();

  int wv = t >> 6;        // wave 0..7
  int l  = t & 63;
  int s  = l >> 2;        // dst slot within wave (0..15)
  int q  = l & 3;         // channel quad: channels 16q..16q+15, heads 2q,2q+1
  int d2 = s * 8 + wv;    // 0..127, balanced across waves

  if (d2 < HSZ) {
    int dst = b * BSZ + dlo + d2;

    // self weights for heads 2q, 2q+1
    float2 sa2 = __half22float2(*(const __half2*)(a_srch + dst * 8 + q * 2));
    float2 ad2 = *(const float2*)(a_dst + dst * 8 + q * 2);
    float z0 = sa2.x + ad2.x, z1 = sa2.y + ad2.y;
    float den0 = __expf(fmaxf(z0, 0.2f * z0));
    float den1 = __expf(fmaxf(z1, 0.2f * z1));

    // acc init = selfw * x_self (16 channels)
    uint4 xs = *(const uint4*)(xw8 + (size_t)dst * 64 + q * 16);
    float xv[16];
    cvt4(xs.x, xv); cvt4(xs.y, xv + 4); cvt4(xs.z, xv + 8); cvt4(xs.w, xv + 12);
    float acc[16];
    #pragma unroll
    for (int c = 0; c < 8; c++) { acc[c] = den0 * xv[c]; acc[8 + c] = den1 * xv[8 + c]; }

    int beg = loff[d2]; if (beg > CAPH) beg = CAPH;
    int end2 = beg + lcnt[d2]; if (end2 > CAPH) end2 = CAPH;

    // 2-deep rotation: indices from LDS, loads independent
    int nA = (beg < end2) ? ssrc[beg] : 0;
    int nB = (beg + 1 < end2) ? ssrc[beg + 1] : 0;
    __half2 aA = *(const __half2*)(a_srch + nA * 8 + q * 2);
    uint4   xA = *(const uint4*)(xw8 + (size_t)nA * 64 + q * 16);
    __half2 aB = *(const __half2*)(a_srch + nB * 8 + q * 2);
    uint4   xB = *(const uint4*)(xw8 + (size_t)nB * 64 + q * 16);

    for (int i = beg; i < end2; i++) {
      float2 af = __half22float2(aA);
      uint4  xc = xA;
      aA = aB; xA = xB;
      int nn = (i + 2 < end2) ? ssrc[i + 2] : 0;
      aB = *(const __half2*)(a_srch + nn * 8 + q * 2);
      xB = *(const uint4*)(xw8 + (size_t)nn * 64 + q * 16);

      float e0 = af.x + ad2.x, e1 = af.y + ad2.y;
      float w0 = __expf(fmaxf(e0, 0.2f * e0));
      float w1 = __expf(fmaxf(e1, 0.2f * e1));
      den0 += w0; den1 += w1;
      float yv[16];
      cvt4(xc.x, yv); cvt4(xc.y, yv + 4); cvt4(xc.z, yv + 8); cvt4(xc.w, yv + 12);
      #pragma unroll
      for (int c = 0; c < 8; c++) { acc[c] += w0 * yv[c]; acc[8 + c] += w1 * yv[8 + c]; }
    }

    // epilogue: divide, bias, relu, pack 16 bf16 = 32B
    float inv0 = __builtin_amdgcn_rcpf(den0);
    float inv1 = __builtin_amdgcn_rcpf(den1);
    uint4 bb0 = ((const uint4*)bias)[q * 2];
    uint4 bb1 = ((const uint4*)bias)[q * 2 + 1];
    unsigned bw[8] = {bb0.x, bb0.y, bb0.z, bb0.w, bb1.x, bb1.y, bb1.z, bb1.w};
    unsigned ow[8];
    #pragma unroll
    for (int p = 0; p < 8; p++) {
      float inv = (p < 4) ? inv0 : inv1;
      float v0 = acc[p * 2]     * inv + b2f((unsigned short)(bw[p] & 0xffff));
      float v1 = acc[p * 2 + 1] * inv + b2f((unsigned short)(bw[p] >> 16));
      v0 = fmaxf(v0, 0.f); v1 = fmaxf(v1, 0.f);
      ow[p] = (unsigned)f2b(v0) | ((unsigned)f2b(v1) << 16);
    }
    uint4 o0 = make_uint4(ow[0], ow[1], ow[2], ow[3]);
    uint4 o1 = make_uint4(ow[4], ow[5], ow[6], ow[7]);
    ((uint4*)nembh)[(size_t)dst * 8 + q * 2]     = o0;
    ((uint4*)nembh)[(size_t)dst * 8 + q * 2 + 1] = o1;
  }
}

// ---- K6: padded gather from bf16 nemb -> fp32 out + seq_lengths tail ----
__global__ __launch_bounds__(256) void k6_gather(
    const unsigned short* __restrict__ nembh, const int* __restrict__ traj,
    const int* __restrict__ lens, float* __restrict__ out)
{
  int gid = blockIdx.x * 256 + threadIdx.x;
  if (gid < BATCHC * MAXLENC * 16) {
    int b = gid >> 15;
    int rem = gid & 32767;
    int l = rem >> 4;
    int ch = rem & 15;
    int len = clampi(lens[b], 0, MAXLENC);
    float4 val = make_float4(0.f, 0.f, 0.f, 0.f);
    if (l < len) {
      int node = clampi(traj[b * MAXLENC + l], 0, N_NODESC - 1);
      uint2 q = ((const uint2*)nembh)[(size_t)node * 16 + ch];
      val = make_float4(b2f((unsigned short)(q.x & 0xffff)),
                        b2f((unsigned short)(q.x >> 16)),
                        b2f((unsigned short)(q.y & 0xffff)),
                        b2f((unsigned short)(q.y >> 16)));
    }
    ((float4*)out)[gid] = val;
  }
  if (gid < BATCHC) {
    out[(size_t)BATCHC * MAXLENC * FEATC + gid] = (float)lens[gid];
  }
}

extern "C" void kernel_launch(void* const* d_in, const int* in_sizes, int n_in,
                              void* d_out, int out_size, void* d_ws, size_t ws_size,
                              hipStream_t stream) {
  const unsigned short* x    = (const unsigned short*)d_in[0];
  const unsigned short* W    = (const unsigned short*)d_in[1];
  const unsigned short* attS = (const unsigned short*)d_in[2];
  const unsigned short* attD = (const unsigned short*)d_in[3];
  const unsigned short* bias = (const unsigned short*)d_in[4];
  const int* ei   = (const int*)d_in[5];
  const int* traj = (const int*)d_in[6];
  const int* lens = (const int*)d_in[7];
  float* out = (float*)d_out;

  // workspace (float units, max 9.9M floats = 39.6 MB; under proven size):
  //  [0, 1.6M)        xw fp8 (6.4M bytes)
  //  [3.2M, 3.6M)     a_src fp16 (800k half)
  //  [4.0M, 4.8M)     a_dst fp32
  //  [4.9M, +512)     ccounts (500)
  //  [+512, +1024)    gcur (500, zero-based)   -- one memset covers both
  //  [+1024, +1536)   boff (500, written by k_csort block 0)
  //  [5.0M, 6.6M)     cs (packed uint, 1.6M)
  //  [6.7M, 9.9M)     nemb bf16 (6.4M ushort)
  float* F = (float*)d_ws;
  unsigned char* xw8 = (unsigned char*)d_ws;
  __half* a_srch = (__half*)(F + 3200000);
  float* a_dst   = F + 4000000;
  int* ccounts   = (int*)(F + 4900000);
  int* gcur      = (int*)(F + 4900000) + 512;
  int* boff      = (int*)(F + 4900000) + 1024;
  unsigned* cs   = (unsigned*)(F + 5000000);
  unsigned short* nembh = (unsigned short*)(F + 6700000);

  hipMemsetAsync(ccounts, 0, 1024 * sizeof(int), stream);
  k_pre<<<K1B + K2B, 256, 0, stream>>>(
      x, W, attS, attD, ei, xw8, a_srch, a_dst, ccounts);
  k_csort<<<(N_EDGESC + P3_EDGES - 1) / P3_EDGES, 1024, 0, stream>>>(ei, ccounts, gcur, cs, boff);
  k_aggf<<<NBUCK * 2, 512, 0, stream>>>(a_srch, a_dst, xw8, cs, ccounts, boff, bias, nembh);
  k6_gather<<<(BATCHC * MAXLENC * 16 + 255) / 256, 256, 0, stream>>>(nembh, traj, lens, out);
}